// Round 14
// baseline (359.693 us; speedup 1.0000x reference)
//
#include <hip/hip_runtime.h>
#include <hip/hip_fp16.h>
#include <cstdint>

#define N_NODES 50000
#define IN_DIM  256
#define HID     128
#define OUT_DIM 64
#define N_EDGES 800000
#define BATCH   4096
#define BN_EPS  1e-5f
#define SLOPE   0.01f

typedef unsigned short u16;
typedef __attribute__((ext_vector_type(8))) short bf16x8;
typedef __attribute__((ext_vector_type(8))) _Float16 f16x8;
typedef __attribute__((ext_vector_type(4))) float f32x4;
typedef __attribute__((ext_vector_type(4))) unsigned u32x4;

__device__ __forceinline__ u16 f2bf(float f) {
    union { float f; unsigned u; } v; v.f = f;
    unsigned r = v.u + 0x7FFF + ((v.u >> 16) & 1);   // RNE
    return (u16)(r >> 16);
}
__device__ __forceinline__ float bf2f(u16 b) {
    union { unsigned u; float f; } v; v.u = ((unsigned)b) << 16;
    return v.f;
}
__device__ __forceinline__ void splitbf(float v, u16* hi, u16* lo) {
    u16 h = f2bf(v);
    *hi = h;
    *lo = f2bf(v - bf2f(h));
}

// Swizzled B store (bf16 hi/lo) for the pool weights.
__device__ __forceinline__ void swz_base(int K, int n, int k, int* base) {
    int KC = K >> 7;
    int chunk = (n >> 6) * KC + (k >> 7);
    *base = chunk * 16384 + ((n >> 4) & 3) * 2048 + ((k >> 5) & 3) * 512
          + (((k >> 3) & 3) * 16 + (n & 15)) * 8 + (k & 7);
}
__device__ __forceinline__ void swz_store(u16* __restrict__ buf, int K, int n, int k, float v) {
    int base; swz_base(K, n, k, &base);
    u16 hi, lo;
    splitbf(v, &hi, &lo);
    buf[base] = hi;
    buf[base + 8192] = lo;
}
// f16 hi/lo variant for the layer weights (consumed by mfma_f32_16x16x32_f16).
__device__ __forceinline__ void swz_store_f16(u16* __restrict__ buf, int K, int n, int k, float v) {
    int base; swz_base(K, n, k, &base);
    __half h = __float2half(v);
    __half l = __float2half(v - __half2float(h));
    buf[base] = *(u16*)&h;
    buf[base + 8192] = *(u16*)&l;
}

// BN partials: 64 spread buffers x 256 floats (sum[128], sumsq[128]) per layer
#define BNP_SPREAD 64
#define BNACC_PER_LAYER (BNP_SPREAD * 256)   // 16384 floats = 64 KB per layer

// ---------------- prep: swizzle weights + transpose + zero-init ----------------
// w0: f16-split swizzle (no BN). wDT: bf16-split (pool path unchanged).
// w1/w2 are swizzled at runtime by scaleB (BN folded in).

#define PW0 (HID * IN_DIM)
#define PWD (PW0 + HID * HID)
#define PWT (PWD + HID * HID)
#define POW (PWT + OUT_DIM * HID)
#define PBN (POW + 3 * BNACC_PER_LAYER)
#define PBC (PBN + 256)

__global__ void prep(const float* __restrict__ w0,
                     const float* __restrict__ WD, const float* __restrict__ WT,
                     const float* __restrict__ out_w,
                     u16* __restrict__ w0swz, u16* __restrict__ wDTswz,
                     float* __restrict__ wt, float* __restrict__ bnacc3,
                     int* __restrict__ bucketCnt) {
    int i = blockIdx.x * 256 + threadIdx.x;
    if (i < PW0) {
        swz_store_f16(w0swz, IN_DIM, i >> 8, i & 255, w0[i]);
    } else if (i < PWD) {
        int j = i - PW0; swz_store(wDTswz, HID, j >> 7, j & 127, WD[j]);
    } else if (i < PWT) {
        int j = i - PWD; swz_store(wDTswz + 32768, HID, j >> 7, j & 127, WT[j]);
    } else if (i < POW) {
        int j = i - PWT;
        wt[j] = out_w[(j & 63) * HID + (j >> 6)];
    } else if (i < PBN) {
        bnacc3[i - POW] = 0.f;
    } else if (i < PBC) {
        bucketCnt[i - PBN] = 0;
    }
}

// ---------------- scaleB: fold BN of layer l-1 into layer-l weights ----------------
// B'_{n,k} = sc_k * W_{n,k}  (f16 hi/lo swizzled);  cbias_n = sum_k sh_k * W_{n,k}.

__global__ __launch_bounds__(256) void scaleB(const float* __restrict__ W,
                                              const float* __restrict__ bnacc,
                                              const float* __restrict__ gamma,
                                              const float* __restrict__ beta,
                                              u16* __restrict__ Bswz,
                                              float* __restrict__ cbias) {
    __shared__ float red[256];
    __shared__ float sc[HID], sh[HID];
    int tid = threadIdx.x;
    float accv = 0.f;
#pragma unroll 8
    for (int p = 0; p < BNP_SPREAD; ++p)
        accv += bnacc[p * 256 + tid];
    red[tid] = accv;
    __syncthreads();
    if (tid < HID) {
        float st = red[tid], sqt = red[HID + tid];
        float mean = st * (1.0f / N_NODES);
        float var  = fmaxf(sqt * (1.0f / N_NODES) - mean * mean, 0.f);
        float s    = gamma[tid] * rsqrtf(var + BN_EPS);
        sc[tid] = s;
        sh[tid] = beta[tid] - mean * s;
    }
    __syncthreads();
    int base = blockIdx.x * 2048 + tid * 8;
#pragma unroll
    for (int u = 0; u < 8; ++u) {
        int j = base + u;
        int n = j >> 7, k = j & 127;
        swz_store_f16(Bswz, HID, n, k, sc[k] * W[j]);
    }
    if (blockIdx.x == 0 && tid < HID) {
        float s = 0.f;
        for (int k = 0; k < HID; ++k)
            s = fmaf(sh[k], W[tid * HID + k], s);
        cbias[tid] = s;
    }
}

// ---------------- bucketed CSR build ----------------

#define NBKT 196
#define PASSA_CHUNK 2048
#define NB_A ((N_EDGES + PASSA_CHUNK - 1) / PASSA_CHUNK)

__global__ void bucket_count(const int* __restrict__ dst, int* __restrict__ bucketCnt) {
    __shared__ int hist[NBKT];
    int t = threadIdx.x;
    if (t < NBKT) hist[t] = 0;
    __syncthreads();
    int b0 = blockIdx.x * PASSA_CHUNK;
    int b1 = min(b0 + PASSA_CHUNK, N_EDGES);
    for (int i = b0 + t; i < b1; i += 256)
        atomicAdd(&hist[dst[i] >> 8], 1);
    __syncthreads();
    if (t < NBKT && hist[t] > 0) atomicAdd(&bucketCnt[t], hist[t]);
}

__global__ void bucket_scan(const int* __restrict__ bucketCnt, int* __restrict__ bucketBase,
                            int* __restrict__ gcursor, int* __restrict__ rowstart) {
    __shared__ int s[256];
    int t = threadIdx.x;
    int v = (t < NBKT) ? bucketCnt[t] : 0;
    s[t] = v;
    __syncthreads();
#pragma unroll
    for (int off = 1; off < 256; off <<= 1) {
        int tmp = (t >= off) ? s[t - off] : 0;
        __syncthreads();
        s[t] += tmp;
        __syncthreads();
    }
    if (t < NBKT) { bucketBase[t] = s[t] - v; gcursor[t] = s[t] - v; }
    if (t == 0) { bucketBase[NBKT] = N_EDGES; rowstart[N_NODES] = N_EDGES; }
}

__global__ void bucket_scatter(const int* __restrict__ src, const int* __restrict__ dst,
                               int* __restrict__ gcursor, unsigned* __restrict__ pairs) {
    __shared__ int hist[NBKT], base[NBKT], hist2[NBKT];
    int t = threadIdx.x;
    if (t < NBKT) { hist[t] = 0; hist2[t] = 0; }
    __syncthreads();
    int b0 = blockIdx.x * PASSA_CHUNK;
    int b1 = min(b0 + PASSA_CHUNK, N_EDGES);
    for (int i = b0 + t; i < b1; i += 256)
        atomicAdd(&hist[dst[i] >> 8], 1);
    __syncthreads();
    if (t < NBKT && hist[t] > 0) base[t] = atomicAdd(&gcursor[t], hist[t]);
    __syncthreads();
    for (int i = b0 + t; i < b1; i += 256) {
        int d = dst[i];
        int b = d >> 8;
        int lp = atomicAdd(&hist2[b], 1);
        pairs[base[b] + lp] = ((unsigned)(d & 255) << 16) | (unsigned)src[i];
    }
}

__global__ void bucket_build(const unsigned* __restrict__ pairs, const int* __restrict__ bucketBase,
                             int* __restrict__ rowstart, float* __restrict__ dinv,
                             u16* __restrict__ csr) {
    __shared__ int cnt[256], s[256], lcur[256];
    int b = blockIdx.x, t = threadIdx.x;
    int pb0 = bucketBase[b], pb1 = bucketBase[b + 1];
    cnt[t] = 0;
    __syncthreads();
    for (int i = pb0 + t; i < pb1; i += 256)
        atomicAdd(&cnt[pairs[i] >> 16], 1);
    __syncthreads();
    int v = cnt[t];
    s[t] = v;
    __syncthreads();
#pragma unroll
    for (int off = 1; off < 256; off <<= 1) {
        int tmp = (t >= off) ? s[t - off] : 0;
        __syncthreads();
        s[t] += tmp;
        __syncthreads();
    }
    int node = (b << 8) + t;
    int start = pb0 + s[t] - v;
    if (node < N_NODES) {
        rowstart[node] = start;
        dinv[node] = rsqrtf(1.0f + (float)v);
    }
    lcur[t] = start;
    __syncthreads();
    for (int i = pb0 + t; i < pb1; i += 256) {
        unsigned pr = pairs[i];
        int pos = atomicAdd(&lcur[pr >> 16], 1);
        csr[pos] = (u16)(pr & 0xFFFFu);   // src node id only (fits 16 bits)
    }
}

// ---------------- f16-MFMA GEMM (layers), full 128-col tiles ----------------
// MODE 0 (layer 0): A fp32, split to f16 hi/lo, 3 MFMA, no BN.
// MODE 1 (layers 1/2): A fp16 direct from memory (zero A-side VALU), B has BN
// scale folded in (scaleB), cbias added in epilogue, 2 MFMA.
// h output pre-scaled by dinv[row], stored slice-blocked hblk[slice][row][32].

template<int MODE>
__global__ __launch_bounds__(256) void gemm_tile(const void* __restrict__ Av,
                                                 const u16* __restrict__ Bswz,
                                                 const float* __restrict__ dinv,
                                                 const float* __restrict__ cbias,
                                                 u16* __restrict__ Cout,
                                                 int M, int K) {
    __shared__ u16 Bs[32768];
    __shared__ float cb_s[HID];
    const int tid  = threadIdx.x;
    const int wave = tid >> 6, lane = tid & 63;
    const int lr   = lane & 15, quad = lane >> 4;
    const int rowBase = blockIdx.x * 64;
    const int KC = K >> 7;

    if (MODE == 1 && tid < HID) cb_s[tid] = cbias[tid];

    f32x4 acc[8];
#pragma unroll
    for (int c = 0; c < 8; ++c) acc[c] = (f32x4){0.f, 0.f, 0.f, 0.f};

    const int arow = rowBase + wave * 16 + lr;
    const bool rv = arow < M;

    for (int kc = 0; kc < KC; ++kc) {
        if (kc) __syncthreads();
        const uint4* s0 = (const uint4*)(Bswz + (size_t)kc * 16384);
        const uint4* s1 = (const uint4*)(Bswz + (size_t)(KC + kc) * 16384);
        uint4* B4 = (uint4*)Bs;
#pragma unroll
        for (int i = 0; i < 8; ++i)
            B4[i * 256 + tid] = s0[i * 256 + tid];
#pragma unroll
        for (int i = 0; i < 8; ++i)
            B4[2048 + i * 256 + tid] = s1[i * 256 + tid];
        __syncthreads();

#pragma unroll
        for (int kkidx = 0; kkidx < 4; ++kkidx) {
            const int kcol = kc * 128 + kkidx * 32 + quad * 8;
            if (MODE == 1) {
                f16x8 a;
#pragma unroll
                for (int j = 0; j < 8; ++j) ((_Float16*)&a)[j] = (_Float16)0.f;
                if (rv)
                    a = *(const f16x8*)((const u16*)Av + (size_t)arow * K + kcol);
#pragma unroll
                for (int c = 0; c < 8; ++c) {
                    const int lb = (c >> 2) * 16384 + (c & 3) * 2048 + kkidx * 512 + lane * 8;
                    f16x8 bh = *(const f16x8*)&Bs[lb];
                    f16x8 bl = *(const f16x8*)&Bs[lb + 8192];
                    acc[c] = __builtin_amdgcn_mfma_f32_16x16x32_f16(a, bh, acc[c], 0, 0, 0);
                    acc[c] = __builtin_amdgcn_mfma_f32_16x16x32_f16(a, bl, acc[c], 0, 0, 0);
                }
            } else {
                float av[8];
                if (rv) {
                    const float* ap = (const float*)Av + (size_t)arow * K + kcol;
                    float4 v0 = ((const float4*)ap)[0];
                    float4 v1 = ((const float4*)ap)[1];
                    av[0] = v0.x; av[1] = v0.y; av[2] = v0.z; av[3] = v0.w;
                    av[4] = v1.x; av[5] = v1.y; av[6] = v1.z; av[7] = v1.w;
                } else {
#pragma unroll
                    for (int j = 0; j < 8; ++j) av[j] = 0.f;
                }
                f16x8 ah, al;
#pragma unroll
                for (int j = 0; j < 8; ++j) {
                    _Float16 h = (_Float16)av[j];
                    ((_Float16*)&ah)[j] = h;
                    ((_Float16*)&al)[j] = (_Float16)(av[j] - (float)h);
                }
#pragma unroll
                for (int c = 0; c < 8; ++c) {
                    const int lb = (c >> 2) * 16384 + (c & 3) * 2048 + kkidx * 512 + lane * 8;
                    f16x8 bh = *(const f16x8*)&Bs[lb];
                    f16x8 bl = *(const f16x8*)&Bs[lb + 8192];
                    acc[c] = __builtin_amdgcn_mfma_f32_16x16x32_f16(al, bh, acc[c], 0, 0, 0);
                    acc[c] = __builtin_amdgcn_mfma_f32_16x16x32_f16(ah, bl, acc[c], 0, 0, 0);
                    acc[c] = __builtin_amdgcn_mfma_f32_16x16x32_f16(ah, bh, acc[c], 0, 0, 0);
                }
            }
        }
    }

    const int rowb = rowBase + wave * 16 + quad * 4;
#pragma unroll
    for (int reg = 0; reg < 4; ++reg) {
        int row = rowb + reg;
        if (row < M) {
            float dn = dinv[row];
#pragma unroll
            for (int c = 0; c < 8; ++c) {
                float v = acc[c][reg];
                if (MODE == 1) v += cb_s[c * 16 + lr];
                __half hv = __float2half(v * dn);
                u16* dst = Cout + (size_t)(c >> 1) * ((size_t)N_NODES * 32)
                         + (size_t)row * 32 + (c & 1) * 16 + lr;
                *dst = *(u16*)&hv;
            }
        }
    }
}

// ---------------- pool GEMM: gathers A from fp16 emb, full 128 cols ----------------

__global__ __launch_bounds__(256) void pool_gemm(const u16* __restrict__ emb0,
                                                 const u16* __restrict__ emb1,
                                                 const u16* __restrict__ emb2,
                                                 const float* __restrict__ bnss3,
                                                 const int* __restrict__ dpos, const int* __restrict__ dneg,
                                                 const int* __restrict__ tpos, const int* __restrict__ tneg,
                                                 const u16* __restrict__ wDTswz,
                                                 const float* __restrict__ q_D, const float* __restrict__ q_T,
                                                 float* __restrict__ e_D, float* __restrict__ e_T) {
    __shared__ u16 Bs[32768];
    const int head = blockIdx.y;
    const u16* Bswz = wDTswz + head * 32768;
    const float* q  = head ? q_T : q_D;
    float* eo = head ? e_T : e_D;
    const int* ia = head ? tpos : dpos;
    const int* ib = head ? tneg : dneg;

    const int tid  = threadIdx.x;
    const int wave = tid >> 6, lane = tid & 63;
    const int lr   = lane & 15, quad = lane >> 4;
    const int rowBase = blockIdx.x * 64;

    const int arow = rowBase + wave * 16 + lr;
    const int l0 = arow >> 13, j0 = arow & 8191;
    const int node0 = (j0 < BATCH) ? ia[j0] : ib[j0 - BATCH];
    const u16* embs[3] = {emb0, emb1, emb2};
    const u16* A0 = embs[l0] + (size_t)node0 * HID;
    const float* bn0 = bnss3 + l0 * 2 * HID;

    f32x4 acc[8];
#pragma unroll
    for (int c = 0; c < 8; ++c) acc[c] = (f32x4){0.f, 0.f, 0.f, 0.f};

    uint4* B4 = (uint4*)Bs;
    const uint4* srcB = (const uint4*)Bswz;
#pragma unroll
    for (int i = 0; i < 16; ++i)
        B4[i * 256 + tid] = srcB[i * 256 + tid];
    __syncthreads();

#pragma unroll
    for (int kkidx = 0; kkidx < 4; ++kkidx) {
        const int kcol = kkidx * 32 + quad * 8;
        float av[8];
        {
            uint4 v = *(const uint4*)(A0 + kcol);
            float2 p0 = __half22float2(*(const __half2*)&v.x);
            float2 p1 = __half22float2(*(const __half2*)&v.y);
            float2 p2 = __half22float2(*(const __half2*)&v.z);
            float2 p3 = __half22float2(*(const __half2*)&v.w);
            av[0] = p0.x; av[1] = p0.y; av[2] = p1.x; av[3] = p1.y;
            av[4] = p2.x; av[5] = p2.y; av[6] = p3.x; av[7] = p3.y;
        }
#pragma unroll
        for (int j = 0; j < 8; ++j)
            av[j] = fmaf(av[j], bn0[kcol + j], bn0[HID + kcol + j]);
        bf16x8 ah, al;
#pragma unroll
        for (int j = 0; j < 8; ++j) {
            u16 hi, lo;
            splitbf(av[j], &hi, &lo);
            ((u16*)&ah)[j] = hi; ((u16*)&al)[j] = lo;
        }
#pragma unroll
        for (int c = 0; c < 8; ++c) {
            const int lb = (c >> 2) * 16384 + (c & 3) * 2048 + kkidx * 512 + lane * 8;
            bf16x8 bh = *(const bf16x8*)&Bs[lb];
            bf16x8 bl = *(const bf16x8*)&Bs[lb + 8192];
            acc[c] = __builtin_amdgcn_mfma_f32_16x16x32_bf16(al, bh, acc[c], 0, 0, 0);
            acc[c] = __builtin_amdgcn_mfma_f32_16x16x32_bf16(ah, bl, acc[c], 0, 0, 0);
            acc[c] = __builtin_amdgcn_mfma_f32_16x16x32_bf16(ah, bh, acc[c], 0, 0, 0);
        }
    }

    float qv[8];
#pragma unroll
    for (int c = 0; c < 8; ++c) qv[c] = q[c * 16 + lr];
    const int rowb = rowBase + wave * 16 + quad * 4;
#pragma unroll
    for (int reg = 0; reg < 4; ++reg) {
        float p = 0.f;
#pragma unroll
        for (int c = 0; c < 8; ++c) {
            float v = acc[c][reg];
            v = (v > 0.f) ? v : SLOPE * v;
            p = fmaf(v, qv[c], p);
        }
        p += __shfl_xor(p, 1);
        p += __shfl_xor(p, 2);
        p += __shfl_xor(p, 4);
        p += __shfl_xor(p, 8);
        if (lr == 0) eo[rowb + reg] = p;   // one block owns each row: plain store
    }
}

// ---------------- GCN aggregation: feature-sliced, XCD-pinned, full-MLP ----------------
// blockIdx&7 -> XCD (round-robin). XCD pair {2s,2s+1} owns feature slice s
// (32 feats = 3.2 MB of hblk, L2-resident). Wave = 16 node-slots x 4 lanes,
// each lane loads uint4 (16B) quarter of the 64B slice row, 4-edge unroll.

#define AGG_NG ((N_NODES + 127) / 128)   // 391 groups; (g,sub) covers 64 nodes

__global__ __launch_bounds__(256) void agg_slice(const u16* __restrict__ hblk,
                                                 const float* __restrict__ dinv,
                                                 const int* __restrict__ rowstart,
                                                 const u16* __restrict__ csr,
                                                 const float* __restrict__ bias,
                                                 u16* __restrict__ out,
                                                 float* __restrict__ bnpart) {
    __shared__ float s_s[32], s_sq[32];
    const int tid  = threadIdx.x;
    const int wave = tid >> 6, lane = tid & 63;
    const int slot = lane >> 2;    // node slot 0..15
    const int ql   = lane & 3;     // uint4 quarter (8 halves) of the 64B slice row
    const int x = blockIdx.x & 7;  // XCD id (heuristic)
    const int slice = x >> 1, sub = x & 1;
    const int g = blockIdx.x >> 3;
    const u16* hs = hblk + (size_t)slice * ((size_t)N_NODES * 32);
    if (tid < 32) { s_s[tid] = 0.f; s_sq[tid] = 0.f; }
    __syncthreads();

    float bs[8], bq[8];
#pragma unroll
    for (int j = 0; j < 8; ++j) { bs[j] = 0.f; bq[j] = 0.f; }

    int n = ((g * 2 + sub) * 4 + wave) * 16 + slot;
    if (n < N_NODES) {
        int s = rowstart[n], e1 = rowstart[n + 1];
        float a[8];
#pragma unroll
        for (int j = 0; j < 8; ++j) a[j] = 0.f;

        int e = s;
        for (; e + 3 < e1; e += 4) {
            int c0 = csr[e], c1 = csr[e + 1], c2 = csr[e + 2], c3 = csr[e + 3];
            uint4 w0 = ((const uint4*)(hs + (size_t)c0 * 32))[ql];
            uint4 w1 = ((const uint4*)(hs + (size_t)c1 * 32))[ql];
            uint4 w2 = ((const uint4*)(hs + (size_t)c2 * 32))[ql];
            uint4 w3 = ((const uint4*)(hs + (size_t)c3 * 32))[ql];
            {
                float2 p0 = __half22float2(*(const __half2*)&w0.x);
                float2 p1 = __half22float2(*(const __half2*)&w0.y);
                float2 p2 = __half22float2(*(const __half2*)&w0.z);
                float2 p3 = __half22float2(*(const __half2*)&w0.w);
                a[0] += p0.x; a[1] += p0.y; a[2] += p1.x; a[3] += p1.y;
                a[4] += p2.x; a[5] += p2.y; a[6] += p3.x; a[7] += p3.y;
            }
            {
                float2 p0 = __half22float2(*(const __half2*)&w1.x);
                float2 p1 = __half22float2(*(const __half2*)&w1.y);
                float2 p2 = __half22float2(*(const __half2*)&w1.z);
                float2 p3 = __half22float2(*(const __half2*)&w1.w);
                a[0] += p0.x; a[1] += p0.y; a[2] += p1.x; a[3] += p1.y;
                a[4] += p2.x; a[5] += p2.y; a[6] += p3.x; a[7] += p3.y;
            }
            {
                float2 p0 = __half22float2(*(const __half2*)&w2.x);
                float2 p1 = __half22float2(*(const __half2*)&w2.y);
                float2 p2 = __half22float2(*(const __half2*)&w2.z);
                float2 p3 = __half22float2(*(const __half2*)&w2.w);
                a[0] += p0.x; a[1] += p0.y; a[2] += p1.x; a[3] += p1.y;
                a[4] += p2.x; a[5] += p2.y; a[6] += p3.x; a[7] += p3.y;
            }
            {
                float2 p0 = __half22float2(*(const __half2*)&w3.x);
                float2 p1 = __half22float2(*(const __half2*)&w3.y);
                float2 p2 = __half22float2(*(const __half2*)&w3.z);
                float2 p3 = __half22float2(*(const __half2*)&w3.w);
                a[0] += p0.x; a[1] += p0.y; a[2] += p1.x; a[3] += p1.y;
                a[4] += p2.x; a[5] += p2.y; a[6] += p3.x; a[7] += p3.y;
            }
        }
        for (; e < e1; ++e) {
            int c0 = csr[e];
            uint4 w0 = ((const uint4*)(hs + (size_t)c0 * 32))[ql];
            float2 p0 = __half22float2(*(const __half2*)&w0.x);
            float2 p1 = __half22float2(*(const __half2*)&w0.y);
            float2 p2 = __half22float2(*(const __half2*)&w0.z);
            float2 p3 = __half22float2(*(const __half2*)&w0.w);
            a[0] += p0.x; a[1] += p0.y; a[2] += p1.x; a[3] += p1.y;
            a[4] += p2.x; a[5] += p2.y; a[6] += p3.x; a[7] += p3.y;
        }

        // epilogue: h pre-scaled -> o = relu(dn*(sum + h'self) + bias)
        float dn = dinv[n];
        uint4 hw = ((const uint4*)(hs + (size_t)n * 32))[ql];
        float2 h0 = __half22float2(*(const __half2*)&hw.x);
        float2 h1 = __half22float2(*(const __half2*)&hw.y);
        float2 h2 = __half22float2(*(const __half2*)&hw.z);
        float2 h3 = __half22float2(*(const __half2*)&hw.w);
        float hv[8] = {h0.x, h0.y, h1.x, h1.y, h2.x, h2.y, h3.x, h3.y};
        float4 bv0 = ((const float4*)(bias + slice * 32 + ql * 8))[0];
        float4 bv1 = ((const float4*)(bias + slice * 32 + ql * 8))[1];
        float bb[8] = {bv0.x, bv0.y, bv0.z, bv0.w, bv1.x, bv1.y, bv1.z, bv1.w};
        float o[8];
#pragma unroll
        for (int j = 0; j < 8; ++j) {
            o[j] = fmaxf(fmaf(dn, a[j] + hv[j], bb[j]), 0.f);
            bs[j] += o[j];
            bq[j] = fmaf(o[j], o[j], bq[j]);
        }
        __half2 q0 = __floats2half2_rn(o[0], o[1]);
        __half2 q1 = __floats2half2_rn(o[2], o[3]);
        __half2 q2 = __floats2half2_rn(o[4], o[5]);
        __half2 q3 = __floats2half2_rn(o[6], o[7]);
        u32x4 ov;
        ov.x = *(unsigned*)&q0; ov.y = *(unsigned*)&q1;
        ov.z = *(unsigned*)&q2; ov.w = *(unsigned*)&q3;
        __builtin_nontemporal_store(ov, (u32x4*)(out + (size_t)n * HID + slice * 32) + ql);
    }

    // BN partials: reduce across the 16 slots (lane bits 2..5), then LDS, then global
#pragma unroll
    for (int j = 0; j < 8; ++j) {
        bs[j] += __shfl_xor(bs[j], 4);
        bs[j] += __shfl_xor(bs[j], 8);
        bs[j] += __shfl_xor(bs[j], 16);
        bs[j] += __shfl_xor(bs[j], 32);
        bq[j] += __shfl_xor(bq[j], 4);
        bq[j] += __shfl_xor(bq[j], 8);
        bq[j] += __shfl_xor(bq[j], 16);
        bq[j] += __shfl_xor(bq[j], 32);
    }
    if (slot == 0) {
#pragma unroll
        for (int j = 0; j < 8; ++j) {
            atomicAdd(&s_s[ql * 8 + j], bs[j]);
            atomicAdd(&s_sq[ql * 8 + j], bq[j]);
        }
    }
    __syncthreads();
    float* bp = bnpart + (size_t)(blockIdx.x & (BNP_SPREAD - 1)) * 256;
    if (tid < 32)      atomicAdd(&bp[slice * 32 + tid], s_s[tid]);
    else if (tid < 64) atomicAdd(&bp[128 + slice * 32 + (tid - 32)], s_sq[tid - 32]);
}

// ---------------- batched BN finalize: one block per layer (for pool/head) ----------------

__global__ void bn_finalize3(const float* __restrict__ bnacc3,
                             const float* __restrict__ gamma, const float* __restrict__ beta,
                             float* __restrict__ bnss3) {
    int l = blockIdx.x;
    int f = threadIdx.x;   // 0..127
    const float* acc = bnacc3 + (size_t)l * BNACC_PER_LAYER;
    float st = 0.f, sqt = 0.f;
    for (int p = 0; p < BNP_SPREAD; ++p) {
        st  += acc[p * 256 + f];
        sqt += acc[p * 256 + HID + f];
    }
    float mean = st * (1.0f / N_NODES);
    float var  = fmaxf(sqt * (1.0f / N_NODES) - mean * mean, 0.f);
    float sc   = gamma[f] * rsqrtf(var + BN_EPS);
    bnss3[l * 2 * HID + f] = sc;
    bnss3[l * 2 * HID + HID + f] = beta[f] - mean * sc;
}

// ---------------- fused softmax-pool + output head (fp16 emb) ----------------

__global__ __launch_bounds__(256) void head_fused(const u16* __restrict__ emb0,
                                                  const u16* __restrict__ emb1,
                                                  const u16* __restrict__ emb2,
                                                  const float* __restrict__ bnss3,
                                                  const int* __restrict__ dpos, const int* __restrict__ dneg,
                                                  const int* __restrict__ tpos, const int* __restrict__ tneg,
                                                  const float* __restrict__ e_D, const float* __restrict__ e_T,
                                                  const float* __restrict__ B,
                                                  const float* __restrict__ bias,
                                                  float* __restrict__ out) {
    __shared__ float Pl[HID][64];     // 32 KB, P transposed: Pl[f][r]
    __shared__ float Bs[32][OUT_DIM]; // 8 KB
    const int y = blockIdx.y;
    const int head = y & 1, seg = y >> 1;
    const int* ia = head ? tpos : dpos;
    const int* ib = head ? tneg : dneg;
    const float* e = head ? e_T : e_D;
    const int tid = threadIdx.x;

    // ---- phase 1: fill Pl ----
    {
        int r = tid >> 2;          // row 0..63 within block
        int part = tid & 3;        // feature quarter
        int p = seg * BATCH + blockIdx.x * 64 + r;   // row in [0, 2*BATCH)
        int node = (p < BATCH) ? ia[p] : ib[p - BATCH];
        float l0 = e[p], l1 = e[2 * BATCH + p], l2 = e[4 * BATCH + p];
        float m = fmaxf(l0, fmaxf(l1, l2));
        float a0 = expf(l0 - m), a1 = expf(l1 - m), a2 = expf(l2 - m);
        float inv = 1.0f / (a0 + a1 + a2);
        a0 *= inv; a1 *= inv; a2 *= inv;
        const u16* r0 = emb0 + (size_t)node * HID + part * 32;
        const u16* r1 = emb1 + (size_t)node * HID + part * 32;
        const u16* r2 = emb2 + (size_t)node * HID + part * 32;
#pragma unroll
        for (int c = 0; c < 32; c += 8) {
            uint4 v0 = *(const uint4*)(r0 + c);
            uint4 v1 = *(const uint4*)(r1 + c);
            uint4 v2 = *(const uint4*)(r2 + c);
            int f = part * 32 + c;
            float e0v[8], e1v[8], e2v[8];
            {
                float2 p0 = __half22float2(*(const __half2*)&v0.x);
                float2 p1 = __half22float2(*(const __half2*)&v0.y);
                float2 p2 = __half22float2(*(const __half2*)&v0.z);
                float2 p3 = __half22float2(*(const __half2*)&v0.w);
                e0v[0] = p0.x; e0v[1] = p0.y; e0v[2] = p1.x; e0v[3] = p1.y;
                e0v[4] = p2.x; e0v[5] = p2.y; e0v[6] = p3.x; e0v[7] = p3.y;
            }
            {
                float2 p0 = __half22float2(*(const __half2*)&v1.x);
                float2 p1 = __half22float2(*(const __half2*)&v1.y);
                float2 p2 = __half22float2(*(const __half2*)&v1.z);
                float2 p3 = __half22float2(*(const __half2*)&v1.w);
                e1v[0] = p0.x; e1v[1] = p0.y; e1v[2] = p1.x; e1v[3] = p1.y;
                e1v[4] = p2.x; e1v[5] = p2.y; e1v[6] = p3.x; e1v[7] = p3.y;
            }
            {
                float2 p0 = __half22float2(*(const __half2*)&v2.x);
                float2 p1 = __half22float2(*(const __half2*)&v2.y);
                float2 p2 = __half22float2(*(const __half2*)&v2.z);
                float2 p3 = __half22float2(*(const __half2*)&v2.w);
                e2v[0] = p0.x; e2v[1] = p0.y; e2v[2] = p1.x; e2v[3] = p1.y;
                e2v[4] = p2.x; e2v[5] = p2.y; e2v[6] = p3.x; e2v[7] = p3.y;
            }
#pragma unroll
            for (int u = 0; u < 8; ++u) {
                float b0 = fmaf(e0v[u], bnss3[f + u],           bnss3[HID + f + u]);
                float b1 = fmaf(e1v[u], bnss3[2 * HID + f + u], bnss3[3 * HID + f + u]);
                float b2 = fmaf(e2v[u], bnss3[4 * HID + f + u], bnss3[5 * HID + f + u]);
                Pl[f + u][r] = a0 * b0 + a1 * b1 + a2 * b2;
            }
        }
    }
    __syncthreads();

    // ---- phase 2: GEMM ----
    const int tx = tid & 15, ty = tid >> 4;
    float acc[4][4];
#pragma unroll
    for (int i = 0; i < 4; ++i)
#pragma unroll
        for (int j = 0; j < 4; ++j) acc[i][j] = 0.f;

    for (int kk = 0; kk < HID; kk += 32) {
        if (kk) __syncthreads();
#pragma unroll
        for (int i = tid; i < (32 * OUT_DIM) / 4; i += 256) {
            int k  = i >> 4;          // 16 float4 per row of 64
            int n4 = i & 15;
            *(float4*)&Bs[k][n4 * 4] = *(const float4*)(B + (size_t)(kk + k) * OUT_DIM + n4 * 4);
        }
        __syncthreads();
#pragma unroll 8
        for (int k = 0; k < 32; ++k) {
            float a[4], b[4];
#pragma unroll
            for (int i = 0; i < 4; ++i) a[i] = Pl[kk + k][ty * 4 + i];
#pragma unroll
            for (int j = 0; j < 4; ++j) b[j] = Bs[k][tx * 4 + j];
#pragma unroll
            for (int i = 0; i < 4; ++i)
#pragma unroll
                for (int j = 0; j < 4; ++j)
                    acc[i][j] = fmaf(a[i], b[j], acc[i][j]);
        }
    }

    float* C = out + (size_t)y * BATCH * OUT_DIM + (size_t)(blockIdx.x * 64) * OUT_DIM;
#pragma unroll
    for (int i = 0; i < 4; ++i) {
        int r = ty * 4 + i;
#pragma unroll
        for (int j = 0; j < 4; ++j)
            C[(size_t)r * OUT_DIM + tx * 4 + j] = acc[i][j] + bias[tx * 4 + j];
    }
}

// ---------------- host ----------------

extern "C" void kernel_launch(void* const* d_in, const int* in_sizes, int n_in,
                              void* d_out, int out_size, void* d_ws, size_t ws_size,
                              hipStream_t stream) {
    const float* x          = (const float*)d_in[0];
    const int*   ei         = (const int*)d_in[1];
    const int*   srcp       = ei;
    const int*   dstp       = ei + N_EDGES;
    const int*   drug_pos   = (const int*)d_in[2];
    const int*   target_pos = (const int*)d_in[3];
    const int*   drug_neg   = (const int*)d_in[4];
    const int*   target_neg = (const int*)d_in[5];
    const float* gcn_w[3]   = {(const float*)d_in[7], (const float*)d_in[9], (const float*)d_in[11]};
    const float* gcn_b[3]   = {(const float*)d_in[8], (const float*)d_in[10], (const float*)d_in[12]};
    const float* gamma      = (const float*)d_in[13];
    const float* beta       = (const float*)d_in[14];
    const float* W_D        = (const float*)d_in[15];
    const float* W_T        = (const float*)d_in[16];
    const float* q_D        = (const float*)d_in[17];
    const float* q_T        = (const float*)d_in[18];
    const float* out_w      = (const float*)d_in[19];
    const float* out_b      = (const float*)d_in[20];
    float*       out        = (float*)d_out;

    // ---- workspace with phase overlays ----
    char* p = (char*)d_ws;
    auto alloc = [&](size_t bytes) -> char* {
        char* r = p;
        p += (bytes + 255) & ~(size_t)255;
        return r;
    };
    char*  reg1  = alloc(sizeof(float) * (size_t)N_NODES * HID);   // hblk (fp16)
    u16*   emb0  = (u16*)alloc(sizeof(u16) * (size_t)N_NODES * HID);
    u16*   emb1  = (u16*)alloc(sizeof(u16) * (size_t)N_NODES * HID);
    u16*   emb2  = (u16*)alloc(sizeof(u16) * (size_t)N_NODES * HID);
    float* ebuf  = (float*)alloc(sizeof(float) * (size_t)2 * 3 * 2 * BATCH);
    u16*   w0swz = (u16*)alloc(sizeof(u16) * 2 * HID * IN_DIM);
    u16*   w1swz = (u16*)alloc(sizeof(u16) * 2 * HID * HID);
    u16*   w2swz = (u16*)alloc(sizeof(u16) * 2 * HID * HID);
    u16*   wDTswz = (u16*)alloc(sizeof(u16) * 4 * HID * HID);
    float* wt    = (float*)alloc(sizeof(float) * OUT_DIM * HID);
    float* cbias12 = (float*)alloc(sizeof(float) * 2 * HID);
    int*   rowstart = (int*)alloc(sizeof(int) * (N_NODES + 1));
    u16*   csr   = (u16*)alloc(sizeof(int) * N_EDGES);   // u16 entries; oversized alloc kept
    unsigned* pairs = (unsigned*)alloc(sizeof(unsigned) * N_EDGES);
    float* dinvp = (float*)alloc(sizeof(float) * N_NODES);
    int*   bucketCnt  = (int*)alloc(sizeof(int) * 256);
    int*   bucketBase = (int*)alloc(sizeof(int) * (NBKT + 1));
    int*   gcursor    = (int*)alloc(sizeof(int) * 256);
    float* bnacc3 = (float*)alloc(sizeof(float) * 3 * BNACC_PER_LAYER);
    float* bnss3  = (float*)alloc(sizeof(float) * 3 * 2 * HID);
    if ((size_t)(p - (char*)d_ws) > ws_size) return;   // visible failure if ws too small

    u16*   hbuf = (u16*)reg1;
    float* e_D  = ebuf;
    float* e_T  = ebuf + 3 * 2 * BATCH;
    u16*   embp[3] = {emb0, emb1, emb2};
    u16*   wswz[3] = {w0swz, w1swz, w2swz};

    // ---- prep ----
    prep<<<(PBC + 255) / 256, 256, 0, stream>>>(
        gcn_w[0], W_D, W_T, out_w, w0swz, wDTswz, wt, bnacc3, bucketCnt);

    // ---- bucketed CSR build ----
    bucket_count<<<NB_A, 256, 0, stream>>>(dstp, bucketCnt);
    bucket_scan<<<1, 256, 0, stream>>>(bucketCnt, bucketBase, gcursor, rowstart);
    bucket_scatter<<<NB_A, 256, 0, stream>>>(srcp, dstp, gcursor, pairs);
    bucket_build<<<NBKT, 256, 0, stream>>>(pairs, bucketBase, rowstart, dinvp, csr);

    // ---- 3 GCN layers (BN folded into layer weights by scaleB) ----
    const int GB = (N_NODES + 63) / 64;   // 782 blocks, full 128-col tiles
    for (int l = 0; l < 3; ++l) {
        int din = (l == 0) ? IN_DIM : HID;
        if (l == 0) {
            gemm_tile<0><<<GB, 256, 0, stream>>>(
                x, wswz[0], dinvp, nullptr, hbuf, N_NODES, din);
        } else {
            scaleB<<<8, 256, 0, stream>>>(
                gcn_w[l], bnacc3 + (size_t)(l - 1) * BNACC_PER_LAYER, gamma, beta,
                wswz[l], cbias12 + (size_t)(l - 1) * HID);
            gemm_tile<1><<<GB, 256, 0, stream>>>(
                embp[l - 1], wswz[l], dinvp, cbias12 + (size_t)(l - 1) * HID,
                hbuf, N_NODES, din);
        }
        agg_slice<<<AGG_NG * 8, 256, 0, stream>>>(hbuf, dinvp, rowstart, csr, gcn_b[l],
                                                  embp[l], bnacc3 + (size_t)l * BNACC_PER_LAYER);
    }

    // ---- BN scale/shift for all 3 layers (for pool/head), one dispatch ----
    bn_finalize3<<<3, HID, 0, stream>>>(bnacc3, gamma, beta, bnss3);

    // ---- attention pooling (H never materialized; e written directly) ----
    const int RG = 3 * 2 * BATCH;
    pool_gemm<<<dim3(RG / 64, 2), 256, 0, stream>>>(
        emb0, emb1, emb2, bnss3, drug_pos, drug_neg, target_pos, target_neg,
        wDTswz, q_D, q_T, e_D, e_T);

    // ---- fused softmax-pool + output head ----
    head_fused<<<dim3(BATCH / 64, 4), 256, 0, stream>>>(
        emb0, emb1, emb2, bnss3, drug_pos, drug_neg, target_pos, target_neg,
        e_D, e_T, wt, out_b, out);
}

// Round 16
// 353.186 us; speedup vs baseline: 1.0184x; 1.0184x over previous
//
#include <hip/hip_runtime.h>
#include <hip/hip_fp16.h>
#include <cstdint>

#define N_NODES 50000
#define IN_DIM  256
#define HID     128
#define OUT_DIM 64
#define N_EDGES 800000
#define BATCH   4096
#define BN_EPS  1e-5f
#define SLOPE   0.01f

typedef unsigned short u16;
typedef __attribute__((ext_vector_type(8))) short bf16x8;
typedef __attribute__((ext_vector_type(4))) float f32x4;
typedef __attribute__((ext_vector_type(4))) unsigned u32x4;

__device__ __forceinline__ u16 f2bf(float f) {
    union { float f; unsigned u; } v; v.f = f;
    unsigned r = v.u + 0x7FFF + ((v.u >> 16) & 1);   // RNE
    return (u16)(r >> 16);
}
__device__ __forceinline__ float bf2f(u16 b) {
    union { unsigned u; float f; } v; v.u = ((unsigned)b) << 16;
    return v.f;
}
__device__ __forceinline__ void splitbf(float v, u16* hi, u16* lo) {
    u16 h = f2bf(v);
    *hi = h;
    *lo = f2bf(v - bf2f(h));
}

// Swizzled B store: element (n,k) of W[128][K] -> fragment-ordered buffer.
__device__ __forceinline__ void swz_store(u16* __restrict__ buf, int K, int n, int k, float v) {
    int KC = K >> 7;
    int chunk = (n >> 6) * KC + (k >> 7);
    int base = chunk * 16384 + ((n >> 4) & 3) * 2048 + ((k >> 5) & 3) * 512
             + (((k >> 3) & 3) * 16 + (n & 15)) * 8 + (k & 7);
    u16 hi, lo;
    splitbf(v, &hi, &lo);
    buf[base] = hi;
    buf[base + 8192] = lo;
}

// BN partials: 64 spread buffers x 256 floats (sum[128], sumsq[128]) per layer
#define BNP_SPREAD 64
#define BNACC_PER_LAYER (BNP_SPREAD * 256)   // 16384 floats = 64 KB per layer

// ---------------- prep: swizzle-split weights + transpose + zero-init ----------------

#define PW0 (HID * IN_DIM)
#define PW1 (PW0 + HID * HID)
#define PW2 (PW1 + HID * HID)
#define PWD (PW2 + HID * HID)
#define PWT (PWD + HID * HID)
#define POW (PWT + OUT_DIM * HID)
#define PBN (POW + 3 * BNACC_PER_LAYER)
#define PBC (PBN + 256)

__global__ void prep(const float* __restrict__ w0, const float* __restrict__ w1,
                     const float* __restrict__ w2, const float* __restrict__ WD,
                     const float* __restrict__ WT, const float* __restrict__ out_w,
                     u16* __restrict__ w0swz, u16* __restrict__ w1swz, u16* __restrict__ w2swz,
                     u16* __restrict__ wDTswz,
                     float* __restrict__ wt, float* __restrict__ bnacc3,
                     int* __restrict__ bucketCnt) {
    int i = blockIdx.x * 256 + threadIdx.x;
    if (i < PW0) {
        swz_store(w0swz, IN_DIM, i >> 8, i & 255, w0[i]);
    } else if (i < PW1) {
        int j = i - PW0; swz_store(w1swz, HID, j >> 7, j & 127, w1[j]);
    } else if (i < PW2) {
        int j = i - PW1; swz_store(w2swz, HID, j >> 7, j & 127, w2[j]);
    } else if (i < PWD) {
        int j = i - PW2; swz_store(wDTswz, HID, j >> 7, j & 127, WD[j]);
    } else if (i < PWT) {
        int j = i - PWD; swz_store(wDTswz + 32768, HID, j >> 7, j & 127, WT[j]);
    } else if (i < POW) {
        int j = i - PWT;
        wt[j] = out_w[(j & 63) * HID + (j >> 6)];
    } else if (i < PBN) {
        bnacc3[i - POW] = 0.f;
    } else if (i < PBC) {
        bucketCnt[i - PBN] = 0;
    }
}

// ---------------- bucketed CSR build ----------------

#define NBKT 196
#define PASSA_CHUNK 2048
#define NB_A ((N_EDGES + PASSA_CHUNK - 1) / PASSA_CHUNK)

__global__ void bucket_count(const int* __restrict__ dst, int* __restrict__ bucketCnt) {
    __shared__ int hist[NBKT];
    int t = threadIdx.x;
    if (t < NBKT) hist[t] = 0;
    __syncthreads();
    int b0 = blockIdx.x * PASSA_CHUNK;
    int b1 = min(b0 + PASSA_CHUNK, N_EDGES);
    for (int i = b0 + t; i < b1; i += 256)
        atomicAdd(&hist[dst[i] >> 8], 1);
    __syncthreads();
    if (t < NBKT && hist[t] > 0) atomicAdd(&bucketCnt[t], hist[t]);
}

__global__ void bucket_scan(const int* __restrict__ bucketCnt, int* __restrict__ bucketBase,
                            int* __restrict__ gcursor, int* __restrict__ rowstart) {
    __shared__ int s[256];
    int t = threadIdx.x;
    int v = (t < NBKT) ? bucketCnt[t] : 0;
    s[t] = v;
    __syncthreads();
#pragma unroll
    for (int off = 1; off < 256; off <<= 1) {
        int tmp = (t >= off) ? s[t - off] : 0;
        __syncthreads();
        s[t] += tmp;
        __syncthreads();
    }
    if (t < NBKT) { bucketBase[t] = s[t] - v; gcursor[t] = s[t] - v; }
    if (t == 0) { bucketBase[NBKT] = N_EDGES; rowstart[N_NODES] = N_EDGES; }
}

__global__ void bucket_scatter(const int* __restrict__ src, const int* __restrict__ dst,
                               int* __restrict__ gcursor, unsigned* __restrict__ pairs) {
    __shared__ int hist[NBKT], base[NBKT], hist2[NBKT];
    int t = threadIdx.x;
    if (t < NBKT) { hist[t] = 0; hist2[t] = 0; }
    __syncthreads();
    int b0 = blockIdx.x * PASSA_CHUNK;
    int b1 = min(b0 + PASSA_CHUNK, N_EDGES);
    for (int i = b0 + t; i < b1; i += 256)
        atomicAdd(&hist[dst[i] >> 8], 1);
    __syncthreads();
    if (t < NBKT && hist[t] > 0) base[t] = atomicAdd(&gcursor[t], hist[t]);
    __syncthreads();
    for (int i = b0 + t; i < b1; i += 256) {
        int d = dst[i];
        int b = d >> 8;
        int lp = atomicAdd(&hist2[b], 1);
        pairs[base[b] + lp] = ((unsigned)(d & 255) << 16) | (unsigned)src[i];
    }
}

__global__ void bucket_build(const unsigned* __restrict__ pairs, const int* __restrict__ bucketBase,
                             int* __restrict__ rowstart, float* __restrict__ dinv,
                             u16* __restrict__ csr) {
    __shared__ int cnt[256], s[256], lcur[256];
    int b = blockIdx.x, t = threadIdx.x;
    int pb0 = bucketBase[b], pb1 = bucketBase[b + 1];
    cnt[t] = 0;
    __syncthreads();
    for (int i = pb0 + t; i < pb1; i += 256)
        atomicAdd(&cnt[pairs[i] >> 16], 1);
    __syncthreads();
    int v = cnt[t];
    s[t] = v;
    __syncthreads();
#pragma unroll
    for (int off = 1; off < 256; off <<= 1) {
        int tmp = (t >= off) ? s[t - off] : 0;
        __syncthreads();
        s[t] += tmp;
        __syncthreads();
    }
    int node = (b << 8) + t;
    int start = pb0 + s[t] - v;
    if (node < N_NODES) {
        rowstart[node] = start;
        dinv[node] = rsqrtf(1.0f + (float)v);
    }
    lcur[t] = start;
    __syncthreads();
    for (int i = pb0 + t; i < pb1; i += 256) {
        unsigned pr = pairs[i];
        int pos = atomicAdd(&lcur[pr >> 16], 1);
        csr[pos] = (u16)(pr & 0xFFFFu);   // src node id only (fits 16 bits)
    }
}

// ---------------- swizzled-B LDS MFMA GEMM (layers), full 128-col tiles ----------------
// Templated: F16A = A is fp16 emb (layers 1/2); BNA = compute BN scale/shift from
// bnacc partials in a per-block preamble. h output pre-scaled by dinv[row],
// stored SLICE-BLOCKED: hblk[slice][row][32] fp16 (64 B rows) so the aggregation
// kernel's per-XCD slice working set (3.2 MB) is L2-resident.

template<bool F16A, bool BNA>
__global__ __launch_bounds__(256) void gemm_tile(const void* __restrict__ Av,
                                                 const float* __restrict__ bnacc,
                                                 const float* __restrict__ gamma,
                                                 const float* __restrict__ beta,
                                                 const u16* __restrict__ Bswz,
                                                 const float* __restrict__ dinv,
                                                 u16* __restrict__ Cout,
                                                 int M, int K) {
    __shared__ u16 Bs[32768];
    __shared__ float bnss_s[2 * HID];
    __shared__ float red[256];
    const int tid  = threadIdx.x;
    const int wave = tid >> 6, lane = tid & 63;
    const int lr   = lane & 15, quad = lane >> 4;
    const int rowBase = blockIdx.x * 64;
    const int KC = K >> 7;

    if (BNA) {
        float accv = 0.f;
#pragma unroll 8
        for (int p = 0; p < BNP_SPREAD; ++p)
            accv += bnacc[p * 256 + tid];
        red[tid] = accv;
        __syncthreads();
        if (tid < HID) {
            float st = red[tid], sqt = red[HID + tid];
            float mean = st * (1.0f / N_NODES);
            float var  = fmaxf(sqt * (1.0f / N_NODES) - mean * mean, 0.f);
            float sc   = gamma[tid] * rsqrtf(var + BN_EPS);
            bnss_s[tid] = sc;
            bnss_s[HID + tid] = beta[tid] - mean * sc;
        }
        __syncthreads();
    }

    f32x4 acc[8];
#pragma unroll
    for (int c = 0; c < 8; ++c) acc[c] = (f32x4){0.f, 0.f, 0.f, 0.f};

    const int arow = rowBase + wave * 16 + lr;
    const bool rv = arow < M;

    for (int kc = 0; kc < KC; ++kc) {
        if (kc) __syncthreads();
        const uint4* s0 = (const uint4*)(Bswz + (size_t)kc * 16384);
        const uint4* s1 = (const uint4*)(Bswz + (size_t)(KC + kc) * 16384);
        uint4* B4 = (uint4*)Bs;
#pragma unroll
        for (int i = 0; i < 8; ++i)
            B4[i * 256 + tid] = s0[i * 256 + tid];
#pragma unroll
        for (int i = 0; i < 8; ++i)
            B4[2048 + i * 256 + tid] = s1[i * 256 + tid];
        __syncthreads();

#pragma unroll
        for (int kkidx = 0; kkidx < 4; ++kkidx) {
            const int kcol = kc * 128 + kkidx * 32 + quad * 8;
            float av[8];
            if (rv) {
                if (F16A) {
                    const u16* ap = (const u16*)Av + (size_t)arow * K + kcol;
                    uint4 v = *(const uint4*)ap;
                    float2 p0 = __half22float2(*(const __half2*)&v.x);
                    float2 p1 = __half22float2(*(const __half2*)&v.y);
                    float2 p2 = __half22float2(*(const __half2*)&v.z);
                    float2 p3 = __half22float2(*(const __half2*)&v.w);
                    av[0] = p0.x; av[1] = p0.y; av[2] = p1.x; av[3] = p1.y;
                    av[4] = p2.x; av[5] = p2.y; av[6] = p3.x; av[7] = p3.y;
                } else {
                    const float* ap = (const float*)Av + (size_t)arow * K + kcol;
                    float4 v0 = ((const float4*)ap)[0];
                    float4 v1 = ((const float4*)ap)[1];
                    av[0] = v0.x; av[1] = v0.y; av[2] = v0.z; av[3] = v0.w;
                    av[4] = v1.x; av[5] = v1.y; av[6] = v1.z; av[7] = v1.w;
                }
            } else {
#pragma unroll
                for (int j = 0; j < 8; ++j) av[j] = 0.f;
            }
            if (BNA) {
#pragma unroll
                for (int j = 0; j < 8; ++j) {
                    float sc = bnss_s[kcol + j];
                    float sh = bnss_s[HID + kcol + j];
                    av[j] = fmaf(av[j], sc, sh);
                }
            }
            bf16x8 ah, al;
#pragma unroll
            for (int j = 0; j < 8; ++j) {
                u16 hi, lo;
                splitbf(av[j], &hi, &lo);
                ((u16*)&ah)[j] = hi; ((u16*)&al)[j] = lo;
            }
#pragma unroll
            for (int c = 0; c < 8; ++c) {
                const int lb = (c >> 2) * 16384 + (c & 3) * 2048 + kkidx * 512 + lane * 8;
                bf16x8 bh = *(const bf16x8*)&Bs[lb];
                bf16x8 bl = *(const bf16x8*)&Bs[lb + 8192];
                acc[c] = __builtin_amdgcn_mfma_f32_16x16x32_bf16(al, bh, acc[c], 0, 0, 0);
                acc[c] = __builtin_amdgcn_mfma_f32_16x16x32_bf16(ah, bl, acc[c], 0, 0, 0);
                acc[c] = __builtin_amdgcn_mfma_f32_16x16x32_bf16(ah, bh, acc[c], 0, 0, 0);
            }
        }
    }

    const int rowb = rowBase + wave * 16 + quad * 4;
#pragma unroll
    for (int reg = 0; reg < 4; ++reg) {
        int row = rowb + reg;
        if (row < M) {
            float dn = dinv[row];
#pragma unroll
            for (int c = 0; c < 8; ++c) {
                __half hv = __float2half(acc[c][reg] * dn);
                u16* dst = Cout + (size_t)(c >> 1) * ((size_t)N_NODES * 32)
                         + (size_t)row * 32 + (c & 1) * 16 + lr;
                *dst = *(u16*)&hv;
            }
        }
    }
}

// ---------------- pool GEMM: gathers A from fp16 emb, full 128 cols ----------------

__global__ __launch_bounds__(256) void pool_gemm(const u16* __restrict__ emb0,
                                                 const u16* __restrict__ emb1,
                                                 const u16* __restrict__ emb2,
                                                 const float* __restrict__ bnss3,
                                                 const int* __restrict__ dpos, const int* __restrict__ dneg,
                                                 const int* __restrict__ tpos, const int* __restrict__ tneg,
                                                 const u16* __restrict__ wDTswz,
                                                 const float* __restrict__ q_D, const float* __restrict__ q_T,
                                                 float* __restrict__ e_D, float* __restrict__ e_T) {
    __shared__ u16 Bs[32768];
    const int head = blockIdx.y;
    const u16* Bswz = wDTswz + head * 32768;
    const float* q  = head ? q_T : q_D;
    float* eo = head ? e_T : e_D;
    const int* ia = head ? tpos : dpos;
    const int* ib = head ? tneg : dneg;

    const int tid  = threadIdx.x;
    const int wave = tid >> 6, lane = tid & 63;
    const int lr   = lane & 15, quad = lane >> 4;
    const int rowBase = blockIdx.x * 64;

    const int arow = rowBase + wave * 16 + lr;
    const int l0 = arow >> 13, j0 = arow & 8191;
    const int node0 = (j0 < BATCH) ? ia[j0] : ib[j0 - BATCH];
    const u16* embs[3] = {emb0, emb1, emb2};
    const u16* A0 = embs[l0] + (size_t)node0 * HID;
    const float* bn0 = bnss3 + l0 * 2 * HID;

    f32x4 acc[8];
#pragma unroll
    for (int c = 0; c < 8; ++c) acc[c] = (f32x4){0.f, 0.f, 0.f, 0.f};

    uint4* B4 = (uint4*)Bs;
    const uint4* srcB = (const uint4*)Bswz;
#pragma unroll
    for (int i = 0; i < 16; ++i)
        B4[i * 256 + tid] = srcB[i * 256 + tid];
    __syncthreads();

#pragma unroll
    for (int kkidx = 0; kkidx < 4; ++kkidx) {
        const int kcol = kkidx * 32 + quad * 8;
        float av[8];
        {
            uint4 v = *(const uint4*)(A0 + kcol);
            float2 p0 = __half22float2(*(const __half2*)&v.x);
            float2 p1 = __half22float2(*(const __half2*)&v.y);
            float2 p2 = __half22float2(*(const __half2*)&v.z);
            float2 p3 = __half22float2(*(const __half2*)&v.w);
            av[0] = p0.x; av[1] = p0.y; av[2] = p1.x; av[3] = p1.y;
            av[4] = p2.x; av[5] = p2.y; av[6] = p3.x; av[7] = p3.y;
        }
#pragma unroll
        for (int j = 0; j < 8; ++j)
            av[j] = fmaf(av[j], bn0[kcol + j], bn0[HID + kcol + j]);
        bf16x8 ah, al;
#pragma unroll
        for (int j = 0; j < 8; ++j) {
            u16 hi, lo;
            splitbf(av[j], &hi, &lo);
            ((u16*)&ah)[j] = hi; ((u16*)&al)[j] = lo;
        }
#pragma unroll
        for (int c = 0; c < 8; ++c) {
            const int lb = (c >> 2) * 16384 + (c & 3) * 2048 + kkidx * 512 + lane * 8;
            bf16x8 bh = *(const bf16x8*)&Bs[lb];
            bf16x8 bl = *(const bf16x8*)&Bs[lb + 8192];
            acc[c] = __builtin_amdgcn_mfma_f32_16x16x32_bf16(al, bh, acc[c], 0, 0, 0);
            acc[c] = __builtin_amdgcn_mfma_f32_16x16x32_bf16(ah, bl, acc[c], 0, 0, 0);
            acc[c] = __builtin_amdgcn_mfma_f32_16x16x32_bf16(ah, bh, acc[c], 0, 0, 0);
        }
    }

    float qv[8];
#pragma unroll
    for (int c = 0; c < 8; ++c) qv[c] = q[c * 16 + lr];
    const int rowb = rowBase + wave * 16 + quad * 4;
#pragma unroll
    for (int reg = 0; reg < 4; ++reg) {
        float p = 0.f;
#pragma unroll
        for (int c = 0; c < 8; ++c) {
            float v = acc[c][reg];
            v = (v > 0.f) ? v : SLOPE * v;
            p = fmaf(v, qv[c], p);
        }
        p += __shfl_xor(p, 1);
        p += __shfl_xor(p, 2);
        p += __shfl_xor(p, 4);
        p += __shfl_xor(p, 8);
        if (lr == 0) eo[rowb + reg] = p;   // one block owns each row: plain store
    }
}

// ---------------- GCN aggregation: feature-sliced, XCD-pinned, full-MLP ----------------
// blockIdx&7 -> XCD (round-robin). XCD pair {2s,2s+1} owns feature slice s
// (32 feats = 3.2 MB of hblk, L2-resident). Wave = 16 node-slots x 4 lanes,
// each lane loads uint4 (16B) quarter of the 64B slice row, 4-edge unroll.

#define AGG_NG ((N_NODES + 127) / 128)   // 391 groups; (g,sub) covers 64 nodes

__global__ __launch_bounds__(256) void agg_slice(const u16* __restrict__ hblk,
                                                 const float* __restrict__ dinv,
                                                 const int* __restrict__ rowstart,
                                                 const u16* __restrict__ csr,
                                                 const float* __restrict__ bias,
                                                 u16* __restrict__ out,
                                                 float* __restrict__ bnpart) {
    __shared__ float s_s[32], s_sq[32];
    const int tid  = threadIdx.x;
    const int wave = tid >> 6, lane = tid & 63;
    const int slot = lane >> 2;    // node slot 0..15
    const int ql   = lane & 3;     // uint4 quarter (8 halves) of the 64B slice row
    const int x = blockIdx.x & 7;  // XCD id (heuristic)
    const int slice = x >> 1, sub = x & 1;
    const int g = blockIdx.x >> 3;
    const u16* hs = hblk + (size_t)slice * ((size_t)N_NODES * 32);
    if (tid < 32) { s_s[tid] = 0.f; s_sq[tid] = 0.f; }
    __syncthreads();

    float bs[8], bq[8];
#pragma unroll
    for (int j = 0; j < 8; ++j) { bs[j] = 0.f; bq[j] = 0.f; }

    int n = ((g * 2 + sub) * 4 + wave) * 16 + slot;
    if (n < N_NODES) {
        int s = rowstart[n], e1 = rowstart[n + 1];
        float a[8];
#pragma unroll
        for (int j = 0; j < 8; ++j) a[j] = 0.f;

        int e = s;
        for (; e + 3 < e1; e += 4) {
            int c0 = csr[e], c1 = csr[e + 1], c2 = csr[e + 2], c3 = csr[e + 3];
            uint4 w0 = ((const uint4*)(hs + (size_t)c0 * 32))[ql];
            uint4 w1 = ((const uint4*)(hs + (size_t)c1 * 32))[ql];
            uint4 w2 = ((const uint4*)(hs + (size_t)c2 * 32))[ql];
            uint4 w3 = ((const uint4*)(hs + (size_t)c3 * 32))[ql];
            {
                float2 p0 = __half22float2(*(const __half2*)&w0.x);
                float2 p1 = __half22float2(*(const __half2*)&w0.y);
                float2 p2 = __half22float2(*(const __half2*)&w0.z);
                float2 p3 = __half22float2(*(const __half2*)&w0.w);
                a[0] += p0.x; a[1] += p0.y; a[2] += p1.x; a[3] += p1.y;
                a[4] += p2.x; a[5] += p2.y; a[6] += p3.x; a[7] += p3.y;
            }
            {
                float2 p0 = __half22float2(*(const __half2*)&w1.x);
                float2 p1 = __half22float2(*(const __half2*)&w1.y);
                float2 p2 = __half22float2(*(const __half2*)&w1.z);
                float2 p3 = __half22float2(*(const __half2*)&w1.w);
                a[0] += p0.x; a[1] += p0.y; a[2] += p1.x; a[3] += p1.y;
                a[4] += p2.x; a[5] += p2.y; a[6] += p3.x; a[7] += p3.y;
            }
            {
                float2 p0 = __half22float2(*(const __half2*)&w2.x);
                float2 p1 = __half22float2(*(const __half2*)&w2.y);
                float2 p2 = __half22float2(*(const __half2*)&w2.z);
                float2 p3 = __half22float2(*(const __half2*)&w2.w);
                a[0] += p0.x; a[1] += p0.y; a[2] += p1.x; a[3] += p1.y;
                a[4] += p2.x; a[5] += p2.y; a[6] += p3.x; a[7] += p3.y;
            }
            {
                float2 p0 = __half22float2(*(const __half2*)&w3.x);
                float2 p1 = __half22float2(*(const __half2*)&w3.y);
                float2 p2 = __half22float2(*(const __half2*)&w3.z);
                float2 p3 = __half22float2(*(const __half2*)&w3.w);
                a[0] += p0.x; a[1] += p0.y; a[2] += p1.x; a[3] += p1.y;
                a[4] += p2.x; a[5] += p2.y; a[6] += p3.x; a[7] += p3.y;
            }
        }
        for (; e < e1; ++e) {
            int c0 = csr[e];
            uint4 w0 = ((const uint4*)(hs + (size_t)c0 * 32))[ql];
            float2 p0 = __half22float2(*(const __half2*)&w0.x);
            float2 p1 = __half22float2(*(const __half2*)&w0.y);
            float2 p2 = __half22float2(*(const __half2*)&w0.z);
            float2 p3 = __half22float2(*(const __half2*)&w0.w);
            a[0] += p0.x; a[1] += p0.y; a[2] += p1.x; a[3] += p1.y;
            a[4] += p2.x; a[5] += p2.y; a[6] += p3.x; a[7] += p3.y;
        }

        // epilogue: h pre-scaled -> o = relu(dn*(sum + h'self) + bias)
        float dn = dinv[n];
        uint4 hw = ((const uint4*)(hs + (size_t)n * 32))[ql];
        float2 h0 = __half22float2(*(const __half2*)&hw.x);
        float2 h1 = __half22float2(*(const __half2*)&hw.y);
        float2 h2 = __half22float2(*(const __half2*)&hw.z);
        float2 h3 = __half22float2(*(const __half2*)&hw.w);
        float hv[8] = {h0.x, h0.y, h1.x, h1.y, h2.x, h2.y, h3.x, h3.y};
        float4 bv0 = ((const float4*)(bias + slice * 32 + ql * 8))[0];
        float4 bv1 = ((const float4*)(bias + slice * 32 + ql * 8))[1];
        float bb[8] = {bv0.x, bv0.y, bv0.z, bv0.w, bv1.x, bv1.y, bv1.z, bv1.w};
        float o[8];
#pragma unroll
        for (int j = 0; j < 8; ++j) {
            o[j] = fmaxf(fmaf(dn, a[j] + hv[j], bb[j]), 0.f);
            bs[j] += o[j];
            bq[j] = fmaf(o[j], o[j], bq[j]);
        }
        __half2 q0 = __floats2half2_rn(o[0], o[1]);
        __half2 q1 = __floats2half2_rn(o[2], o[3]);
        __half2 q2 = __floats2half2_rn(o[4], o[5]);
        __half2 q3 = __floats2half2_rn(o[6], o[7]);
        u32x4 ov;
        ov.x = *(unsigned*)&q0; ov.y = *(unsigned*)&q1;
        ov.z = *(unsigned*)&q2; ov.w = *(unsigned*)&q3;
        __builtin_nontemporal_store(ov, (u32x4*)(out + (size_t)n * HID + slice * 32) + ql);
    }

    // BN partials: reduce across the 16 slots (lane bits 2..5), then LDS, then global
#pragma unroll
    for (int j = 0; j < 8; ++j) {
        bs[j] += __shfl_xor(bs[j], 4);
        bs[j] += __shfl_xor(bs[j], 8);
        bs[j] += __shfl_xor(bs[j], 16);
        bs[j] += __shfl_xor(bs[j], 32);
        bq[j] += __shfl_xor(bq[j], 4);
        bq[j] += __shfl_xor(bq[j], 8);
        bq[j] += __shfl_xor(bq[j], 16);
        bq[j] += __shfl_xor(bq[j], 32);
    }
    if (slot == 0) {
#pragma unroll
        for (int j = 0; j < 8; ++j) {
            atomicAdd(&s_s[ql * 8 + j], bs[j]);
            atomicAdd(&s_sq[ql * 8 + j], bq[j]);
        }
    }
    __syncthreads();
    float* bp = bnpart + (size_t)(blockIdx.x & (BNP_SPREAD - 1)) * 256;
    if (tid < 32)      atomicAdd(&bp[slice * 32 + tid], s_s[tid]);
    else if (tid < 64) atomicAdd(&bp[128 + slice * 32 + (tid - 32)], s_sq[tid - 32]);
}

// ---------------- batched BN finalize: one block per layer (for pool/head) ----------------

__global__ void bn_finalize3(const float* __restrict__ bnacc3,
                             const float* __restrict__ gamma, const float* __restrict__ beta,
                             float* __restrict__ bnss3) {
    int l = blockIdx.x;
    int f = threadIdx.x;   // 0..127
    const float* acc = bnacc3 + (size_t)l * BNACC_PER_LAYER;
    float st = 0.f, sqt = 0.f;
    for (int p = 0; p < BNP_SPREAD; ++p) {
        st  += acc[p * 256 + f];
        sqt += acc[p * 256 + HID + f];
    }
    float mean = st * (1.0f / N_NODES);
    float var  = fmaxf(sqt * (1.0f / N_NODES) - mean * mean, 0.f);
    float sc   = gamma[f] * rsqrtf(var + BN_EPS);
    bnss3[l * 2 * HID + f] = sc;
    bnss3[l * 2 * HID + HID + f] = beta[f] - mean * sc;
}

// ---------------- fused softmax-pool + output head (fp16 emb) ----------------

__global__ __launch_bounds__(256) void head_fused(const u16* __restrict__ emb0,
                                                  const u16* __restrict__ emb1,
                                                  const u16* __restrict__ emb2,
                                                  const float* __restrict__ bnss3,
                                                  const int* __restrict__ dpos, const int* __restrict__ dneg,
                                                  const int* __restrict__ tpos, const int* __restrict__ tneg,
                                                  const float* __restrict__ e_D, const float* __restrict__ e_T,
                                                  const float* __restrict__ B,
                                                  const float* __restrict__ bias,
                                                  float* __restrict__ out) {
    __shared__ float Pl[HID][64];     // 32 KB, P transposed: Pl[f][r]
    __shared__ float Bs[32][OUT_DIM]; // 8 KB
    const int y = blockIdx.y;
    const int head = y & 1, seg = y >> 1;
    const int* ia = head ? tpos : dpos;
    const int* ib = head ? tneg : dneg;
    const float* e = head ? e_T : e_D;
    const int tid = threadIdx.x;

    // ---- phase 1: fill Pl ----
    {
        int r = tid >> 2;          // row 0..63 within block
        int part = tid & 3;        // feature quarter
        int p = seg * BATCH + blockIdx.x * 64 + r;   // row in [0, 2*BATCH)
        int node = (p < BATCH) ? ia[p] : ib[p - BATCH];
        float l0 = e[p], l1 = e[2 * BATCH + p], l2 = e[4 * BATCH + p];
        float m = fmaxf(l0, fmaxf(l1, l2));
        float a0 = expf(l0 - m), a1 = expf(l1 - m), a2 = expf(l2 - m);
        float inv = 1.0f / (a0 + a1 + a2);
        a0 *= inv; a1 *= inv; a2 *= inv;
        const u16* r0 = emb0 + (size_t)node * HID + part * 32;
        const u16* r1 = emb1 + (size_t)node * HID + part * 32;
        const u16* r2 = emb2 + (size_t)node * HID + part * 32;
#pragma unroll
        for (int c = 0; c < 32; c += 8) {
            uint4 v0 = *(const uint4*)(r0 + c);
            uint4 v1 = *(const uint4*)(r1 + c);
            uint4 v2 = *(const uint4*)(r2 + c);
            int f = part * 32 + c;
            float e0v[8], e1v[8], e2v[8];
            {
                float2 p0 = __half22float2(*(const __half2*)&v0.x);
                float2 p1 = __half22float2(*(const __half2*)&v0.y);
                float2 p2 = __half22float2(*(const __half2*)&v0.z);
                float2 p3 = __half22float2(*(const __half2*)&v0.w);
                e0v[0] = p0.x; e0v[1] = p0.y; e0v[2] = p1.x; e0v[3] = p1.y;
                e0v[4] = p2.x; e0v[5] = p2.y; e0v[6] = p3.x; e0v[7] = p3.y;
            }
            {
                float2 p0 = __half22float2(*(const __half2*)&v1.x);
                float2 p1 = __half22float2(*(const __half2*)&v1.y);
                float2 p2 = __half22float2(*(const __half2*)&v1.z);
                float2 p3 = __half22float2(*(const __half2*)&v1.w);
                e1v[0] = p0.x; e1v[1] = p0.y; e1v[2] = p1.x; e1v[3] = p1.y;
                e1v[4] = p2.x; e1v[5] = p2.y; e1v[6] = p3.x; e1v[7] = p3.y;
            }
            {
                float2 p0 = __half22float2(*(const __half2*)&v2.x);
                float2 p1 = __half22float2(*(const __half2*)&v2.y);
                float2 p2 = __half22float2(*(const __half2*)&v2.z);
                float2 p3 = __half22float2(*(const __half2*)&v2.w);
                e2v[0] = p0.x; e2v[1] = p0.y; e2v[2] = p1.x; e2v[3] = p1.y;
                e2v[4] = p2.x; e2v[5] = p2.y; e2v[6] = p3.x; e2v[7] = p3.y;
            }
#pragma unroll
            for (int u = 0; u < 8; ++u) {
                float b0 = fmaf(e0v[u], bnss3[f + u],           bnss3[HID + f + u]);
                float b1 = fmaf(e1v[u], bnss3[2 * HID + f + u], bnss3[3 * HID + f + u]);
                float b2 = fmaf(e2v[u], bnss3[4 * HID + f + u], bnss3[5 * HID + f + u]);
                Pl[f + u][r] = a0 * b0 + a1 * b1 + a2 * b2;
            }
        }
    }
    __syncthreads();

    // ---- phase 2: GEMM ----
    const int tx = tid & 15, ty = tid >> 4;
    float acc[4][4];
#pragma unroll
    for (int i = 0; i < 4; ++i)
#pragma unroll
        for (int j = 0; j < 4; ++j) acc[i][j] = 0.f;

    for (int kk = 0; kk < HID; kk += 32) {
        if (kk) __syncthreads();
#pragma unroll
        for (int i = tid; i < (32 * OUT_DIM) / 4; i += 256) {
            int k  = i >> 4;          // 16 float4 per row of 64
            int n4 = i & 15;
            *(float4*)&Bs[k][n4 * 4] = *(const float4*)(B + (size_t)(kk + k) * OUT_DIM + n4 * 4);
        }
        __syncthreads();
#pragma unroll 8
        for (int k = 0; k < 32; ++k) {
            float a[4], b[4];
#pragma unroll
            for (int i = 0; i < 4; ++i) a[i] = Pl[kk + k][ty * 4 + i];
#pragma unroll
            for (int j = 0; j < 4; ++j) b[j] = Bs[k][tx * 4 + j];
#pragma unroll
            for (int i = 0; i < 4; ++i)
#pragma unroll
                for (int j = 0; j < 4; ++j)
                    acc[i][j] = fmaf(a[i], b[j], acc[i][j]);
        }
    }

    float* C = out + (size_t)y * BATCH * OUT_DIM + (size_t)(blockIdx.x * 64) * OUT_DIM;
#pragma unroll
    for (int i = 0; i < 4; ++i) {
        int r = ty * 4 + i;
#pragma unroll
        for (int j = 0; j < 4; ++j)
            C[(size_t)r * OUT_DIM + tx * 4 + j] = acc[i][j] + bias[tx * 4 + j];
    }
}

// ---------------- host ----------------

extern "C" void kernel_launch(void* const* d_in, const int* in_sizes, int n_in,
                              void* d_out, int out_size, void* d_ws, size_t ws_size,
                              hipStream_t stream) {
    const float* x          = (const float*)d_in[0];
    const int*   ei         = (const int*)d_in[1];
    const int*   srcp       = ei;
    const int*   dstp       = ei + N_EDGES;
    const int*   drug_pos   = (const int*)d_in[2];
    const int*   target_pos = (const int*)d_in[3];
    const int*   drug_neg   = (const int*)d_in[4];
    const int*   target_neg = (const int*)d_in[5];
    const float* gcn_w[3]   = {(const float*)d_in[7], (const float*)d_in[9], (const float*)d_in[11]};
    const float* gcn_b[3]   = {(const float*)d_in[8], (const float*)d_in[10], (const float*)d_in[12]};
    const float* gamma      = (const float*)d_in[13];
    const float* beta       = (const float*)d_in[14];
    const float* W_D        = (const float*)d_in[15];
    const float* W_T        = (const float*)d_in[16];
    const float* q_D        = (const float*)d_in[17];
    const float* q_T        = (const float*)d_in[18];
    const float* out_w      = (const float*)d_in[19];
    const float* out_b      = (const float*)d_in[20];
    float*       out        = (float*)d_out;

    // ---- workspace with phase overlays ----
    char* p = (char*)d_ws;
    auto alloc = [&](size_t bytes) -> char* {
        char* r = p;
        p += (bytes + 255) & ~(size_t)255;
        return r;
    };
    char*  reg1  = alloc(sizeof(float) * (size_t)N_NODES * HID);   // hblk (fp16)
    u16*   emb0  = (u16*)alloc(sizeof(u16) * (size_t)N_NODES * HID);
    u16*   emb1  = (u16*)alloc(sizeof(u16) * (size_t)N_NODES * HID);
    u16*   emb2  = (u16*)alloc(sizeof(u16) * (size_t)N_NODES * HID);
    float* ebuf  = (float*)alloc(sizeof(float) * (size_t)2 * 3 * 2 * BATCH);
    u16*   w0swz = (u16*)alloc(sizeof(u16) * 2 * HID * IN_DIM);
    u16*   w1swz = (u16*)alloc(sizeof(u16) * 2 * HID * HID);
    u16*   w2swz = (u16*)alloc(sizeof(u16) * 2 * HID * HID);
    u16*   wDTswz = (u16*)alloc(sizeof(u16) * 4 * HID * HID);
    float* wt    = (float*)alloc(sizeof(float) * OUT_DIM * HID);
    int*   rowstart = (int*)alloc(sizeof(int) * (N_NODES + 1));
    u16*   csr   = (u16*)alloc(sizeof(int) * N_EDGES);   // u16 entries; oversized alloc kept
    unsigned* pairs = (unsigned*)alloc(sizeof(unsigned) * N_EDGES);
    float* dinvp = (float*)alloc(sizeof(float) * N_NODES);
    int*   bucketCnt  = (int*)alloc(sizeof(int) * 256);
    int*   bucketBase = (int*)alloc(sizeof(int) * (NBKT + 1));
    int*   gcursor    = (int*)alloc(sizeof(int) * 256);
    float* bnacc3 = (float*)alloc(sizeof(float) * 3 * BNACC_PER_LAYER);
    float* bnss3  = (float*)alloc(sizeof(float) * 3 * 2 * HID);
    if ((size_t)(p - (char*)d_ws) > ws_size) return;   // visible failure if ws too small

    u16*   hbuf = (u16*)reg1;
    float* e_D  = ebuf;
    float* e_T  = ebuf + 3 * 2 * BATCH;
    u16*   embp[3] = {emb0, emb1, emb2};
    const u16* wswz[3] = {w0swz, w1swz, w2swz};

    // ---- prep ----
    prep<<<(PBC + 255) / 256, 256, 0, stream>>>(
        gcn_w[0], gcn_w[1], gcn_w[2], W_D, W_T, out_w,
        w0swz, w1swz, w2swz, wDTswz, wt, bnacc3, bucketCnt);

    // ---- bucketed CSR build ----
    bucket_count<<<NB_A, 256, 0, stream>>>(dstp, bucketCnt);
    bucket_scan<<<1, 256, 0, stream>>>(bucketCnt, bucketBase, gcursor, rowstart);
    bucket_scatter<<<NB_A, 256, 0, stream>>>(srcp, dstp, gcursor, pairs);
    bucket_build<<<NBKT, 256, 0, stream>>>(pairs, bucketBase, rowstart, dinvp, csr);

    // ---- 3 GCN layers (BN stats fused into agg; BN applied in next consumer,
    //      consumer computes scale/shift from partials in-block) ----
    const int GB = (N_NODES + 63) / 64;   // 782 blocks, full 128-col tiles
    for (int l = 0; l < 3; ++l) {
        int din = (l == 0) ? IN_DIM : HID;
        if (l == 0)
            gemm_tile<false, false><<<GB, 256, 0, stream>>>(
                x, nullptr, nullptr, nullptr, wswz[l], dinvp, hbuf, N_NODES, din);
        else
            gemm_tile<true, true><<<GB, 256, 0, stream>>>(
                embp[l - 1], bnacc3 + (size_t)(l - 1) * BNACC_PER_LAYER, gamma, beta,
                wswz[l], dinvp, hbuf, N_NODES, din);
        agg_slice<<<AGG_NG * 8, 256, 0, stream>>>(hbuf, dinvp, rowstart, csr, gcn_b[l],
                                                  embp[l], bnacc3 + (size_t)l * BNACC_PER_LAYER);
    }

    // ---- BN scale/shift for all 3 layers (for pool/head), one dispatch ----
    bn_finalize3<<<3, HID, 0, stream>>>(bnacc3, gamma, beta, bnss3);

    // ---- attention pooling (H never materialized; e written directly) ----
    const int RG = 3 * 2 * BATCH;
    pool_gemm<<<dim3(RG / 64, 2), 256, 0, stream>>>(
        emb0, emb1, emb2, bnss3, drug_pos, drug_neg, target_pos, target_neg,
        wDTswz, q_D, q_T, e_D, e_T);

    // ---- fused softmax-pool + output head ----
    head_fused<<<dim3(BATCH / 64, 4), 256, 0, stream>>>(
        emb0, emb1, emb2, bnss3, drug_pos, drug_neg, target_pos, target_neg,
        e_D, e_T, wt, out_b, out);
}